// Round 6
// baseline (686.052 us; speedup 1.0000x reference)
//
#include <hip/hip_runtime.h>
#include <stdint.h>

using bf16   = __bf16;
using bf16x4 = __attribute__((ext_vector_type(4))) __bf16;
using bf16x8 = __attribute__((ext_vector_type(8))) __bf16;
using f32x4  = __attribute__((ext_vector_type(4))) float;

#define DEV_INLINE __device__ __forceinline__

// async global->LDS, 16B per lane. LDS base must be wave-uniform; HW adds lane*16.
DEV_INLINE void gload16(const void* g, const void* l) {
  __builtin_amdgcn_global_load_lds(
      (const __attribute__((address_space(1))) unsigned int*)(uintptr_t)g,
      (__attribute__((address_space(3))) unsigned int*)(unsigned int)(uintptr_t)l,
      16, 0, 0);
}

DEV_INLINE f32x4 mfma16(bf16x8 a, bf16x8 b, f32x4 c) {
  return __builtin_amdgcn_mfma_f32_16x16x32_bf16(a, b, c, 0, 0, 0);
}

#define WAIT_LGKM0() do { \
  asm volatile("s_waitcnt lgkmcnt(0)" ::: "memory"); \
  __builtin_amdgcn_sched_barrier(0); } while (0)

// ---------------- cast x (fp32 -> bf16) ----------------
__global__ void cast_f32_bf16(const float4* __restrict__ in, bf16* __restrict__ out, int n4) {
  int i = blockIdx.x * 256 + threadIdx.x;
  if (i >= n4) return;
  float4 v = in[i];
  bf16x4 o = { (bf16)v.x, (bf16)v.y, (bf16)v.z, (bf16)v.w };
  *(bf16x4*)(out + (size_t)i * 4) = o;
}

// ---------------- transpose+cast: in [rows][cols] f32 -> out [cols][rows] bf16 ----
__global__ void transpose_cast(const float* __restrict__ in, bf16* __restrict__ out,
                               int rows, int cols) {
  __shared__ float tile[32][33];
  int c0 = blockIdx.x * 32, r0 = blockIdx.y * 32;
  int t = threadIdx.x, tc = t & 31, tr = t >> 5;
  for (int i = 0; i < 4; ++i)
    tile[tr + i*8][tc] = in[(size_t)(r0 + tr + i*8) * cols + (c0 + tc)];
  __syncthreads();
  for (int i = 0; i < 4; ++i)
    out[(size_t)(c0 + tr + i*8) * rows + (r0 + tc)] = (bf16)tile[tc][tr + i*8];
}

// ================= 256x256 8-phase GEMM core (T1+T3+T4+T5) =================
// BM=BN=256, BK=64, 8 waves (512 thr). LDS = 4 half-slots/operand x 16KB = 128KB.
// Fragment-linear LDS layout => zero bank conflicts, matches global_load_lds.
// Slot ring: slot(X half, kt) = (2kt+half)&3; counted vmcnt(4) once per K-tile.

DEV_INLINE void stage_half(const bf16* __restrict__ src, int K, int k0, bf16* slot,
                           int w, int lr, int lc) {
#pragma unroll
  for (int i = 0; i < 2; ++i)
    gload16(src + (size_t)(w*16 + lr) * K + (k0 + i*32 + lc*8), slot + (w*2 + i) * 512);
}

DEV_INLINE void load_afr(bf16x8 (&af)[4][2], const bf16* slot, int wr2, int l) {
#pragma unroll
  for (int mi = 0; mi < 4; ++mi)
#pragma unroll
    for (int ks = 0; ks < 2; ++ks)
      af[mi][ks] = *(const bf16x8*)(slot + ((wr2*4 + mi)*2 + ks) * 512 + l*8);
}

template<bool PERM>
DEV_INLINE void load_bfr(bf16x8 (&bfr)[2][2], const bf16* slot, int wc2, int l) {
#pragma unroll
  for (int ni = 0; ni < 2; ++ni)
#pragma unroll
    for (int ks = 0; ks < 2; ++ks) {
      int mt = PERM ? (ni*4 + wc2) : (wc2*2 + ni);   // PERM: wave holds (d, d+64) pair
      bfr[ni][ks] = *(const bf16x8*)(slot + (mt*2 + ks) * 512 + l*8);
    }
}

DEV_INLINE void mfma_quad(f32x4 (&aq)[4][2], const bf16x8 (&af)[4][2],
                          const bf16x8 (&bfr)[2][2]) {
#pragma unroll
  for (int mi = 0; mi < 4; ++mi)
#pragma unroll
    for (int ni = 0; ni < 2; ++ni)
#pragma unroll
      for (int ks = 0; ks < 2; ++ks)
        aq[mi][ni] = mfma16(af[mi][ks], bfr[ni][ks], aq[mi][ni]);
}

template<bool PERM, int K, int NK>
DEV_INLINE void gemm256_core(const bf16* __restrict__ A, const bf16* __restrict__ Bt,
                             int bm0, int bn0, bf16* sA, bf16* sB,
                             int w, int l, int lr, int lc, int wr2, int wc2,
                             f32x4 (&acc)[2][2][4][2]) {
  const bf16* Ar0 = A  + (size_t)bm0 * K;
  const bf16* Ar1 = Ar0 + (size_t)128 * K;
  const bf16* Br0 = Bt + (size_t)bn0 * K;
  const bf16* Br1 = Br0 + (size_t)128 * K;
  stage_half(Ar0, K, 0,  sA + 0*8192, w, lr, lc);
  stage_half(Br1, K, 0,  sB + 1*8192, w, lr, lc);
  stage_half(Ar1, K, 0,  sA + 1*8192, w, lr, lc);
  stage_half(Br0, K, 0,  sB + 0*8192, w, lr, lc);
  stage_half(Ar0, K, 64, sA + 2*8192, w, lr, lc);
  stage_half(Br1, K, 64, sB + 3*8192, w, lr, lc);
  __syncthreads();

  for (int kt = 0; kt < NK; ++kt) {
    const int k1 = (kt + 1 < NK ? kt + 1 : 0) * 64;   // wrap keeps vmcnt math uniform
    const int k2 = (kt + 2 < NK ? kt + 2 : 0) * 64;
    bf16* A0s = sA + ((2*kt    ) & 3) * 8192;
    bf16* A1s = sA + ((2*kt + 1) & 3) * 8192;
    bf16* B0s = sB + ((2*kt    ) & 3) * 8192;
    bf16* B1s = sB + ((2*kt + 1) & 3) * 8192;
    bf16x8 af[4][2], bfr[2][2];

    // phase 0: quadrant (mh=0,nh=0); stage A1(kt+1)
    load_afr(af, A0s, wr2, l);
    load_bfr<PERM>(bfr, B0s, wc2, l);
    stage_half(Ar1, K, k1, sA + ((2*kt + 3) & 3) * 8192, w, lr, lc);
    __builtin_amdgcn_s_barrier();
    WAIT_LGKM0();
    __builtin_amdgcn_s_setprio(1);
    mfma_quad(acc[0][0], af, bfr);
    __builtin_amdgcn_s_setprio(0);
    __builtin_amdgcn_s_barrier();

    // phase 1: quadrant (0,1); stage B0(kt+1)
    load_bfr<PERM>(bfr, B1s, wc2, l);
    stage_half(Br0, K, k1, sB + ((2*kt + 2) & 3) * 8192, w, lr, lc);
    __builtin_amdgcn_s_barrier();
    WAIT_LGKM0();
    __builtin_amdgcn_s_setprio(1);
    mfma_quad(acc[0][1], af, bfr);
    __builtin_amdgcn_s_setprio(0);
    __builtin_amdgcn_s_barrier();

    // phase 2: quadrant (1,1); stage A0(kt+2) into A0(kt)'s slot (freed after ph0)
    load_afr(af, A1s, wr2, l);
    stage_half(Ar0, K, k2, sA + ((2*kt + 4) & 3) * 8192, w, lr, lc);
    __builtin_amdgcn_s_barrier();
    WAIT_LGKM0();
    __builtin_amdgcn_s_setprio(1);
    mfma_quad(acc[1][1], af, bfr);
    __builtin_amdgcn_s_setprio(0);
    __builtin_amdgcn_s_barrier();

    // phase 3: quadrant (1,0); stage B1(kt+2); counted vmcnt(4) = K-tile gate
    load_bfr<PERM>(bfr, B0s, wc2, l);
    stage_half(Br1, K, k2, sB + ((2*kt + 5) & 3) * 8192, w, lr, lc);
    __builtin_amdgcn_s_barrier();
    WAIT_LGKM0();
    __builtin_amdgcn_s_setprio(1);
    mfma_quad(acc[1][0], af, bfr);
    __builtin_amdgcn_s_setprio(0);
    asm volatile("s_waitcnt vmcnt(4)" ::: "memory");
    __builtin_amdgcn_sched_barrier(0);
    __builtin_amdgcn_s_barrier();
  }
  asm volatile("s_waitcnt vmcnt(0)" ::: "memory");   // drain before LDS teardown
}

// ---------------- QKV GEMM (256^2) with fused RoPE epilogue ----------------
__global__ __launch_bounds__(512, 2)
void gemm256_rope(const bf16* __restrict__ A, const bf16* __restrict__ Bt,
                  const float* __restrict__ cs, const float* __restrict__ sn,
                  bf16* __restrict__ Qr, bf16* __restrict__ Kr,
                  bf16* __restrict__ Vbuf) {
  __shared__ bf16 sA[4 * 8192];
  __shared__ bf16 sB[4 * 8192];
  int id = blockIdx.x;
  int swz = (id & 7) * 64 + (id >> 3);     // bijective XCD swizzle, 512 blocks
  int tm = swz >> 4, tn = swz & 15;
  int bm0 = tm * 256, bn0 = tn * 256;
  int tid = threadIdx.x, w = tid >> 6, l = tid & 63, lr = l & 15, lc = l >> 4;
  int wr2 = w >> 2, wc2 = w & 3;
  f32x4 acc[2][2][4][2] = {};
  gemm256_core<true, 2048, 32>(A, Bt, bm0, bn0, sA, sB, w, l, lr, lc, wr2, wc2, acc);

  int bb = bm0 >> 11, s0 = bm0 & 2047;     // 256 | 2048 -> b uniform per block
  int dlo = wc2 * 16 + lr;                 // < 64
#pragma unroll
  for (int nh = 0; nh < 2; ++nh) {
    int h128 = tn * 2 + nh;
    if (h128 < 24) {
      // RoPE path: Q (h128<16) or K. Q gets log2e/sqrt(128) folded in.
      const float scale = (h128 < 16) ? 0.08838834764831845f * 1.4426950408889634f : 1.0f;
      bf16* dstB = (h128 < 16)
          ? Qr + (size_t)(bb * 16 + h128) * 2048 * 128
          : Kr + (size_t)(bb * 8 + (h128 - 16)) * 2048 * 128;
#pragma unroll
      for (int mh = 0; mh < 2; ++mh)
#pragma unroll
        for (int mi = 0; mi < 4; ++mi)
#pragma unroll
          for (int r = 0; r < 4; ++r) {
            int sl = s0 + mh*128 + wr2*64 + mi*16 + lc*4 + r;
            float c  = cs[sl * 128 + dlo];
            float sv = sn[sl * 128 + dlo];
            float lo = acc[mh][nh][mi][0][r], hi = acc[mh][nh][mi][1][r];
            bf16* dst = dstB + (size_t)sl * 128 + dlo;
            dst[0]  = (bf16)((lo * c - hi * sv) * scale);
            dst[64] = (bf16)((hi * c + lo * sv) * scale);
          }
    } else {
      int kvh = h128 - 24;                 // V path: plain store
#pragma unroll
      for (int mh = 0; mh < 2; ++mh)
#pragma unroll
        for (int mi = 0; mi < 4; ++mi)
#pragma unroll
          for (int r = 0; r < 4; ++r) {
            int sl = s0 + mh*128 + wr2*64 + mi*16 + lc*4 + r;
            bf16* dst = Vbuf + ((size_t)(bb * 2048) + sl) * 1024 + kvh * 128 + dlo;
            dst[0]  = (bf16)acc[mh][nh][mi][0][r];
            dst[64] = (bf16)acc[mh][nh][mi][1][r];
          }
    }
  }
}

// ---------------- out-proj GEMM (256^2), f32 output ----------------
__global__ __launch_bounds__(512, 2)
void gemm256_out(const bf16* __restrict__ A, const bf16* __restrict__ Bt,
                 float* __restrict__ C) {
  __shared__ bf16 sA[4 * 8192];
  __shared__ bf16 sB[4 * 8192];
  int id = blockIdx.x;
  int swz = (id & 7) * 32 + (id >> 3);     // bijective XCD swizzle, 256 blocks
  int tm = swz >> 3, tn = swz & 7;
  int bm0 = tm * 256, bn0 = tn * 256;
  int tid = threadIdx.x, w = tid >> 6, l = tid & 63, lr = l & 15, lc = l >> 4;
  int wr2 = w >> 2, wc2 = w & 3;
  f32x4 acc[2][2][4][2] = {};
  gemm256_core<false, 2048, 32>(A, Bt, bm0, bn0, sA, sB, w, l, lr, lc, wr2, wc2, acc);
#pragma unroll
  for (int mh = 0; mh < 2; ++mh)
#pragma unroll
    for (int nh = 0; nh < 2; ++nh)
#pragma unroll
      for (int mi = 0; mi < 4; ++mi)
#pragma unroll
        for (int ni = 0; ni < 2; ++ni)
#pragma unroll
          for (int r = 0; r < 4; ++r) {
            int row = bm0 + mh*128 + wr2*64 + mi*16 + lc*4 + r;
            int col = bn0 + nh*128 + wc2*32 + ni*16 + lr;
            C[(size_t)row * 2048 + col] = acc[mh][nh][mi][ni][r];
          }
}

// ---------------- V transpose: Vbuf[b*2048+s][kvh*128+d] -> Vt[b*8+h][d][s] ----
__global__ void v_transpose(const bf16* __restrict__ Vbuf, bf16* __restrict__ Vt) {
  __shared__ bf16 tile[32][33];
  int s0 = blockIdx.x * 32, d0 = blockIdx.y * 32, bh = blockIdx.z;
  int b = bh >> 3, h = bh & 7;
  int t = threadIdx.x, tc = t & 31, tr = t >> 5;
  for (int i = 0; i < 4; ++i)
    tile[tr + i*8][tc] =
        Vbuf[((size_t)(b*2048) + s0 + tr + i*8) * 1024 + h*128 + d0 + tc];
  __syncthreads();
  for (int i = 0; i < 4; ++i)
    Vt[((size_t)bh * 128 + d0 + tr + i*8) * 2048 + s0 + tc] = tile[tc][tr + i*8];
}

// ---------------- flash attention, causal, GQA-fused, BN=64 ----------------
// block = 4 waves; both q-heads of one kv-head; BM=64 q rows, BN=64 keys/tile.
// Residency is the measured lever (R2/R3 2 blk/CU=190us, R4 1 blk/CU=258us):
// LDS = K 16KB + V 16KB + P 16KB = 48KB -> 3 blocks/CU co-resident; co-resident
// blocks at different phases cover each other's stage drains.
// Dedicated wave-private sP (no aliasing) -> only 2 barriers per tile:
// loop-top (t-1 reads retired) and post-stage (tile data landed).
// Diagonal remap: co-CU blocks share x, so qi=31-x gave them IDENTICAL tmax
// (worst CU 4x16 tiles); qi=(x+y)&31 spreads tmax by 8 among co-residents.
__global__ __launch_bounds__(256, 3)
void attn_kernel(const bf16* __restrict__ Q, const bf16* __restrict__ Kg,
                 const bf16* __restrict__ Vt, bf16* __restrict__ Og) {
  __shared__ bf16 sK[16 * 512];    // 16KB: K chunks (ntk 0..3)x(ksk 0..3)
  __shared__ bf16 sV[16 * 512];    // 16KB: V chunks (ntd 0..7)x(ksv 0..1)
  __shared__ bf16 sP[8 * 1024];    // 16KB: [head][wave] 1024-elem wave-private slices
  int x = blockIdx.x, y = blockIdx.y;
  int qi = (x + y) & 31;           // diagonal remap (bijective per y)
  int bkv = y;                     // b*8 + kvh
  int b = bkv >> 3, kvh = bkv & 7;
  int tid = threadIdx.x, w = tid >> 6, l = tid & 63, lr = l & 15, lc = l >> 4;
  const bf16* Qb0 = Q + ((size_t)(b*16 + kvh*2) * 2048 + qi*64) * 128;
  const bf16* Qb1 = Qb0 + (size_t)2048 * 128;
  const bf16* Kb  = Kg + (size_t)bkv * 2048 * 128;
  const bf16* Vb  = Vt + (size_t)bkv * 128 * 2048;
  bf16x8 qf0[4], qf1[4];
  for (int ks = 0; ks < 4; ++ks) {
    size_t off = (size_t)(w*16 + lr) * 128 + ks*32 + lc*8;
    qf0[ks] = *(const bf16x8*)(Qb0 + off);
    qf1[ks] = *(const bf16x8*)(Qb1 + off);
  }
  f32x4 o0[8] = {}, o1[8] = {};
  float l0[4] = {0.f,0.f,0.f,0.f}, l1[4] = {0.f,0.f,0.f,0.f};
  int qrow = qi*64 + w*16 + lc*4;      // + r
  bf16* sP0 = sP + w * 1024;           // per-wave [16 q][64 key], XOR swizzle
  bf16* sP1 = sP + 4096 + w * 1024;    // head 1 half
  int tmax = qi + 1;                   // 64-key tiles up to causal boundary
  for (int t = 0; t < tmax; ++t) {
    __syncthreads();                   // K/V reads of t-1 retired -> restage safe
    for (int i = 0; i < 4; ++i) {
      int id = w*4 + i;                // 16 chunks each for K and V
      int ntk = id >> 2, ksk = id & 3; // K chunk: 16 keys x 32 d
      gload16(Kb + (size_t)(t*64 + ntk*16 + lr) * 128 + ksk*32 + lc*8, sK + id*512);
      int ntd = id >> 1, ksv = id & 1; // V chunk: 16 d x 32 keys
      gload16(Vb + (size_t)(ntd*16 + lr) * 2048 + t*64 + ksv*32 + lc*8, sV + id*512);
    }
    __syncthreads();                   // drain: tile data landed
    // S = Q K^T for both heads; K fragments loaded once
    f32x4 s0[4] = {}, s1[4] = {};
    for (int nt = 0; nt < 4; ++nt)
      for (int ks = 0; ks < 4; ++ks) {
        bf16x8 kf = *(const bf16x8*)(sK + (nt*4 + ks)*512 + l*8);
        s0[nt] = mfma16(qf0[ks], kf, s0[nt]);
        s1[nt] = mfma16(qf1[ks], kf, s1[nt]);
      }
    // causal mask: only the diagonal tile needs it (block-uniform branch)
    if (t == tmax - 1) {
      for (int nt = 0; nt < 4; ++nt) {
        int col = t*64 + nt*16 + lr;
        for (int r = 0; r < 4; ++r)
          if (col > qrow + r) { s0[nt][r] = -1e30f; s1[nt][r] = -1e30f; }
      }
    }
    // P phase: wave-private sP slices, no barrier needed vs other waves.
    // P swizzle (64 keys): addr = q*64 + (((key>>3) ^ (q&7))*8) + (key&7)
    for (int nt = 0; nt < 4; ++nt) {
      int blk = nt*2 + (lr >> 3);      // key>>3 in [0,8)
      int off = lr & 7;
      for (int r = 0; r < 4; ++r) {
        int q = lc*4 + r;
        int addr = q*64 + (((blk ^ q) & 7) * 8) + off;
        float p0 = __builtin_amdgcn_exp2f(s0[nt][r]);
        float p1 = __builtin_amdgcn_exp2f(s1[nt][r]);
        l0[r] += p0;
        l1[r] += p1;
        sP0[addr] = (bf16)p0;
        sP1[addr] = (bf16)p1;
      }
    }
    WAIT_LGKM0();                      // same-wave RAW through LDS
    bf16x8 pf0[2], pf1[2];
    for (int ks = 0; ks < 2; ++ks) {
      int ra = lr*64 + (((ks*4 + lc) ^ (lr & 7)) * 8);
      pf0[ks] = *(const bf16x8*)(sP0 + ra);
      pf1[ks] = *(const bf16x8*)(sP1 + ra);
    }
    // PV: V fragments read once, feed both heads
    for (int nt = 0; nt < 8; ++nt)
      for (int ks = 0; ks < 2; ++ks) {
        bf16x8 vf = *(const bf16x8*)(sV + (nt*2 + ks)*512 + l*8);
        o0[nt] = mfma16(pf0[ks], vf, o0[nt]);
        o1[nt] = mfma16(pf1[ks], vf, o1[nt]);
      }
  }
  // deferred l reduction: one shuffle ladder for the whole kernel
  for (int msk = 1; msk < 16; msk <<= 1)
    for (int r = 0; r < 4; ++r) {
      l0[r] += __shfl_xor(l0[r], msk, 64);
      l1[r] += __shfl_xor(l1[r], msk, 64);
    }
  for (int r = 0; r < 4; ++r) {
    float inv0 = 1.f / l0[r];
    float inv1 = 1.f / l1[r];
    size_t row = (size_t)(b*2048) + qi*64 + w*16 + lc*4 + r;
    size_t base0 = row * 2048 + (kvh*2) * 128;
    for (int nt = 0; nt < 8; ++nt) {
      Og[base0 + nt*16 + lr]       = (bf16)(o0[nt][r] * inv0);
      Og[base0 + 128 + nt*16 + lr] = (bf16)(o1[nt][r] * inv1);
    }
  }
}

extern "C" void kernel_launch(void* const* d_in, const int* in_sizes, int n_in,
                              void* d_out, int out_size, void* d_ws, size_t ws_size,
                              hipStream_t stream) {
  (void)in_sizes; (void)n_in; (void)out_size; (void)ws_size;
  const float* x  = (const float*)d_in[0];
  const float* cs = (const float*)d_in[1];
  const float* sn = (const float*)d_in[2];
  const float* Wq = (const float*)d_in[3];
  const float* Wk = (const float*)d_in[4];
  const float* Wv = (const float*)d_in[5];
  const float* Wo = (const float*)d_in[6];
  float* out = (float*)d_out;

  char* p = (char*)d_ws;
  bf16* xb    = (bf16*)p;  p += (size_t)8192*2048*2;    // x bf16
  bf16* Wt    = (bf16*)p;  p += (size_t)4096*2048*2;    // [Wq|Wk|Wv]^T bf16
  bf16* Wot   = (bf16*)p;  p += (size_t)2048*2048*2;    // Wo^T bf16
  bf16* Qr    = (bf16*)p;  p += (size_t)64*2048*128*2;  // Q roped [bh][s][d]
  bf16* Kr    = (bf16*)p;  p += (size_t)32*2048*128*2;  // K roped [bkv][s][d]
  bf16* Vbuf  = (bf16*)p;  p += (size_t)8192*1024*2;    // V [b*2048+s][kvh*128+d]
  bf16* Vtb   = (bf16*)p;  p += (size_t)32*2048*128*2;  // V^T [bkv][d][s]
  bf16* attnb = (bf16*)p;  p += (size_t)8192*2048*2;    // attention out

  cast_f32_bf16<<<4194304/256, 256, 0, stream>>>((const float4*)x, xb, 4194304);
  transpose_cast<<<dim3(64,64), 256, 0, stream>>>(Wq, Wt, 2048, 2048);
  transpose_cast<<<dim3(32,64), 256, 0, stream>>>(Wk, Wt + (size_t)2048*2048, 2048, 1024);
  transpose_cast<<<dim3(32,64), 256, 0, stream>>>(Wv, Wt + (size_t)3072*2048, 2048, 1024);
  transpose_cast<<<dim3(64,64), 256, 0, stream>>>(Wo, Wot, 2048, 2048);
  gemm256_rope<<<dim3(512), 512, 0, stream>>>(xb, Wt, cs, sn, Qr, Kr, Vbuf);
  v_transpose<<<dim3(64,4,32), 256, 0, stream>>>(Vbuf, Vtb);
  attn_kernel<<<dim3(32,32), 256, 0, stream>>>(Qr, Kr, Vtb, attnb);
  gemm256_out<<<dim3(256), 512, 0, stream>>>(attnb, Wot, out);
}

// Round 7
// 541.705 us; speedup vs baseline: 1.2665x; 1.2665x over previous
//
#include <hip/hip_runtime.h>
#include <stdint.h>

using bf16   = __bf16;
using bf16x4 = __attribute__((ext_vector_type(4))) __bf16;
using bf16x8 = __attribute__((ext_vector_type(8))) __bf16;
using f32x4  = __attribute__((ext_vector_type(4))) float;

#define DEV_INLINE __device__ __forceinline__

// async global->LDS, 16B per lane. LDS base must be wave-uniform; HW adds lane*16.
DEV_INLINE void gload16(const void* g, const void* l) {
  __builtin_amdgcn_global_load_lds(
      (const __attribute__((address_space(1))) unsigned int*)(uintptr_t)g,
      (__attribute__((address_space(3))) unsigned int*)(unsigned int)(uintptr_t)l,
      16, 0, 0);
}

DEV_INLINE f32x4 mfma16(bf16x8 a, bf16x8 b, f32x4 c) {
  return __builtin_amdgcn_mfma_f32_16x16x32_bf16(a, b, c, 0, 0, 0);
}

#define WAIT_LGKM0() do { \
  asm volatile("s_waitcnt lgkmcnt(0)" ::: "memory"); \
  __builtin_amdgcn_sched_barrier(0); } while (0)

// ---------------- cast x (fp32 -> bf16) ----------------
__global__ void cast_f32_bf16(const float4* __restrict__ in, bf16* __restrict__ out, int n4) {
  int i = blockIdx.x * 256 + threadIdx.x;
  if (i >= n4) return;
  float4 v = in[i];
  bf16x4 o = { (bf16)v.x, (bf16)v.y, (bf16)v.z, (bf16)v.w };
  *(bf16x4*)(out + (size_t)i * 4) = o;
}

// ---------------- transpose+cast: in [rows][cols] f32 -> out [cols][rows] bf16 ----
__global__ void transpose_cast(const float* __restrict__ in, bf16* __restrict__ out,
                               int rows, int cols) {
  __shared__ float tile[32][33];
  int c0 = blockIdx.x * 32, r0 = blockIdx.y * 32;
  int t = threadIdx.x, tc = t & 31, tr = t >> 5;
  for (int i = 0; i < 4; ++i)
    tile[tr + i*8][tc] = in[(size_t)(r0 + tr + i*8) * cols + (c0 + tc)];
  __syncthreads();
  for (int i = 0; i < 4; ++i)
    out[(size_t)(c0 + tr + i*8) * rows + (r0 + tc)] = (bf16)tile[tc][tr + i*8];
}

// ================= 256x256 8-phase GEMM core (T1+T3+T4+T5) =================
// BM=BN=256, BK=64, 8 waves (512 thr). LDS = 4 half-slots/operand x 16KB = 128KB.
// Fragment-linear LDS layout => zero bank conflicts, matches global_load_lds.
// Slot ring: slot(X half, kt) = (2kt+half)&3; counted vmcnt(4) once per K-tile.

DEV_INLINE void stage_half(const bf16* __restrict__ src, int K, int k0, bf16* slot,
                           int w, int lr, int lc) {
#pragma unroll
  for (int i = 0; i < 2; ++i)
    gload16(src + (size_t)(w*16 + lr) * K + (k0 + i*32 + lc*8), slot + (w*2 + i) * 512);
}

DEV_INLINE void load_afr(bf16x8 (&af)[4][2], const bf16* slot, int wr2, int l) {
#pragma unroll
  for (int mi = 0; mi < 4; ++mi)
#pragma unroll
    for (int ks = 0; ks < 2; ++ks)
      af[mi][ks] = *(const bf16x8*)(slot + ((wr2*4 + mi)*2 + ks) * 512 + l*8);
}

template<bool PERM>
DEV_INLINE void load_bfr(bf16x8 (&bfr)[2][2], const bf16* slot, int wc2, int l) {
#pragma unroll
  for (int ni = 0; ni < 2; ++ni)
#pragma unroll
    for (int ks = 0; ks < 2; ++ks) {
      int mt = PERM ? (ni*4 + wc2) : (wc2*2 + ni);   // PERM: wave holds (d, d+64) pair
      bfr[ni][ks] = *(const bf16x8*)(slot + (mt*2 + ks) * 512 + l*8);
    }
}

DEV_INLINE void mfma_quad(f32x4 (&aq)[4][2], const bf16x8 (&af)[4][2],
                          const bf16x8 (&bfr)[2][2]) {
#pragma unroll
  for (int mi = 0; mi < 4; ++mi)
#pragma unroll
    for (int ni = 0; ni < 2; ++ni)
#pragma unroll
      for (int ks = 0; ks < 2; ++ks)
        aq[mi][ni] = mfma16(af[mi][ks], bfr[ni][ks], aq[mi][ni]);
}

template<bool PERM, int K, int NK>
DEV_INLINE void gemm256_core(const bf16* __restrict__ A, const bf16* __restrict__ Bt,
                             int bm0, int bn0, bf16* sA, bf16* sB,
                             int w, int l, int lr, int lc, int wr2, int wc2,
                             f32x4 (&acc)[2][2][4][2]) {
  const bf16* Ar0 = A  + (size_t)bm0 * K;
  const bf16* Ar1 = Ar0 + (size_t)128 * K;
  const bf16* Br0 = Bt + (size_t)bn0 * K;
  const bf16* Br1 = Br0 + (size_t)128 * K;
  stage_half(Ar0, K, 0,  sA + 0*8192, w, lr, lc);
  stage_half(Br1, K, 0,  sB + 1*8192, w, lr, lc);
  stage_half(Ar1, K, 0,  sA + 1*8192, w, lr, lc);
  stage_half(Br0, K, 0,  sB + 0*8192, w, lr, lc);
  stage_half(Ar0, K, 64, sA + 2*8192, w, lr, lc);
  stage_half(Br1, K, 64, sB + 3*8192, w, lr, lc);
  __syncthreads();

  for (int kt = 0; kt < NK; ++kt) {
    const int k1 = (kt + 1 < NK ? kt + 1 : 0) * 64;   // wrap keeps vmcnt math uniform
    const int k2 = (kt + 2 < NK ? kt + 2 : 0) * 64;
    bf16* A0s = sA + ((2*kt    ) & 3) * 8192;
    bf16* A1s = sA + ((2*kt + 1) & 3) * 8192;
    bf16* B0s = sB + ((2*kt    ) & 3) * 8192;
    bf16* B1s = sB + ((2*kt + 1) & 3) * 8192;
    bf16x8 af[4][2], bfr[2][2];

    // phase 0: quadrant (mh=0,nh=0); stage A1(kt+1)
    load_afr(af, A0s, wr2, l);
    load_bfr<PERM>(bfr, B0s, wc2, l);
    stage_half(Ar1, K, k1, sA + ((2*kt + 3) & 3) * 8192, w, lr, lc);
    __builtin_amdgcn_s_barrier();
    WAIT_LGKM0();
    __builtin_amdgcn_s_setprio(1);
    mfma_quad(acc[0][0], af, bfr);
    __builtin_amdgcn_s_setprio(0);
    __builtin_amdgcn_s_barrier();

    // phase 1: quadrant (0,1); stage B0(kt+1)
    load_bfr<PERM>(bfr, B1s, wc2, l);
    stage_half(Br0, K, k1, sB + ((2*kt + 2) & 3) * 8192, w, lr, lc);
    __builtin_amdgcn_s_barrier();
    WAIT_LGKM0();
    __builtin_amdgcn_s_setprio(1);
    mfma_quad(acc[0][1], af, bfr);
    __builtin_amdgcn_s_setprio(0);
    __builtin_amdgcn_s_barrier();

    // phase 2: quadrant (1,1); stage A0(kt+2) into A0(kt)'s slot (freed after ph0)
    load_afr(af, A1s, wr2, l);
    stage_half(Ar0, K, k2, sA + ((2*kt + 4) & 3) * 8192, w, lr, lc);
    __builtin_amdgcn_s_barrier();
    WAIT_LGKM0();
    __builtin_amdgcn_s_setprio(1);
    mfma_quad(acc[1][1], af, bfr);
    __builtin_amdgcn_s_setprio(0);
    __builtin_amdgcn_s_barrier();

    // phase 3: quadrant (1,0); stage B1(kt+2); counted vmcnt(4) = K-tile gate
    load_bfr<PERM>(bfr, B0s, wc2, l);
    stage_half(Br1, K, k2, sB + ((2*kt + 5) & 3) * 8192, w, lr, lc);
    __builtin_amdgcn_s_barrier();
    WAIT_LGKM0();
    __builtin_amdgcn_s_setprio(1);
    mfma_quad(acc[1][0], af, bfr);
    __builtin_amdgcn_s_setprio(0);
    asm volatile("s_waitcnt vmcnt(4)" ::: "memory");
    __builtin_amdgcn_sched_barrier(0);
    __builtin_amdgcn_s_barrier();
  }
  asm volatile("s_waitcnt vmcnt(0)" ::: "memory");   // drain before LDS teardown
}

// ---------------- QKV GEMM (256^2) with fused RoPE epilogue ----------------
__global__ __launch_bounds__(512, 2)
void gemm256_rope(const bf16* __restrict__ A, const bf16* __restrict__ Bt,
                  const float* __restrict__ cs, const float* __restrict__ sn,
                  bf16* __restrict__ Qr, bf16* __restrict__ Kr,
                  bf16* __restrict__ Vbuf) {
  __shared__ bf16 sA[4 * 8192];
  __shared__ bf16 sB[4 * 8192];
  int id = blockIdx.x;
  int swz = (id & 7) * 64 + (id >> 3);     // bijective XCD swizzle, 512 blocks
  int tm = swz >> 4, tn = swz & 15;
  int bm0 = tm * 256, bn0 = tn * 256;
  int tid = threadIdx.x, w = tid >> 6, l = tid & 63, lr = l & 15, lc = l >> 4;
  int wr2 = w >> 2, wc2 = w & 3;
  f32x4 acc[2][2][4][2] = {};
  gemm256_core<true, 2048, 32>(A, Bt, bm0, bn0, sA, sB, w, l, lr, lc, wr2, wc2, acc);

  int bb = bm0 >> 11, s0 = bm0 & 2047;     // 256 | 2048 -> b uniform per block
  int dlo = wc2 * 16 + lr;                 // < 64
#pragma unroll
  for (int nh = 0; nh < 2; ++nh) {
    int h128 = tn * 2 + nh;
    if (h128 < 24) {
      // RoPE path: Q (h128<16) or K. Q gets log2e/sqrt(128) folded in.
      const float scale = (h128 < 16) ? 0.08838834764831845f * 1.4426950408889634f : 1.0f;
      bf16* dstB = (h128 < 16)
          ? Qr + (size_t)(bb * 16 + h128) * 2048 * 128
          : Kr + (size_t)(bb * 8 + (h128 - 16)) * 2048 * 128;
#pragma unroll
      for (int mh = 0; mh < 2; ++mh)
#pragma unroll
        for (int mi = 0; mi < 4; ++mi)
#pragma unroll
          for (int r = 0; r < 4; ++r) {
            int sl = s0 + mh*128 + wr2*64 + mi*16 + lc*4 + r;
            float c  = cs[sl * 128 + dlo];
            float sv = sn[sl * 128 + dlo];
            float lo = acc[mh][nh][mi][0][r], hi = acc[mh][nh][mi][1][r];
            bf16* dst = dstB + (size_t)sl * 128 + dlo;
            dst[0]  = (bf16)((lo * c - hi * sv) * scale);
            dst[64] = (bf16)((hi * c + lo * sv) * scale);
          }
    } else {
      int kvh = h128 - 24;                 // V path: plain store
#pragma unroll
      for (int mh = 0; mh < 2; ++mh)
#pragma unroll
        for (int mi = 0; mi < 4; ++mi)
#pragma unroll
          for (int r = 0; r < 4; ++r) {
            int sl = s0 + mh*128 + wr2*64 + mi*16 + lc*4 + r;
            bf16* dst = Vbuf + ((size_t)(bb * 2048) + sl) * 1024 + kvh * 128 + dlo;
            dst[0]  = (bf16)acc[mh][nh][mi][0][r];
            dst[64] = (bf16)acc[mh][nh][mi][1][r];
          }
    }
  }
}

// ---------------- out-proj GEMM (256^2), f32 output ----------------
__global__ __launch_bounds__(512, 2)
void gemm256_out(const bf16* __restrict__ A, const bf16* __restrict__ Bt,
                 float* __restrict__ C) {
  __shared__ bf16 sA[4 * 8192];
  __shared__ bf16 sB[4 * 8192];
  int id = blockIdx.x;
  int swz = (id & 7) * 32 + (id >> 3);     // bijective XCD swizzle, 256 blocks
  int tm = swz >> 3, tn = swz & 7;
  int bm0 = tm * 256, bn0 = tn * 256;
  int tid = threadIdx.x, w = tid >> 6, l = tid & 63, lr = l & 15, lc = l >> 4;
  int wr2 = w >> 2, wc2 = w & 3;
  f32x4 acc[2][2][4][2] = {};
  gemm256_core<false, 2048, 32>(A, Bt, bm0, bn0, sA, sB, w, l, lr, lc, wr2, wc2, acc);
#pragma unroll
  for (int mh = 0; mh < 2; ++mh)
#pragma unroll
    for (int nh = 0; nh < 2; ++nh)
#pragma unroll
      for (int mi = 0; mi < 4; ++mi)
#pragma unroll
        for (int ni = 0; ni < 2; ++ni)
#pragma unroll
          for (int r = 0; r < 4; ++r) {
            int row = bm0 + mh*128 + wr2*64 + mi*16 + lc*4 + r;
            int col = bn0 + nh*128 + wc2*32 + ni*16 + lr;
            C[(size_t)row * 2048 + col] = acc[mh][nh][mi][ni][r];
          }
}

// ---------------- V transpose: Vbuf[b*2048+s][kvh*128+d] -> Vt[b*8+h][d][s] ----
__global__ void v_transpose(const bf16* __restrict__ Vbuf, bf16* __restrict__ Vt) {
  __shared__ bf16 tile[32][33];
  int s0 = blockIdx.x * 32, d0 = blockIdx.y * 32, bh = blockIdx.z;
  int b = bh >> 3, h = bh & 7;
  int t = threadIdx.x, tc = t & 31, tr = t >> 5;
  for (int i = 0; i < 4; ++i)
    tile[tr + i*8][tc] =
        Vbuf[((size_t)(b*2048) + s0 + tr + i*8) * 1024 + h*128 + d0 + tc];
  __syncthreads();
  for (int i = 0; i < 4; ++i)
    Vt[((size_t)bh * 128 + d0 + tr + i*8) * 2048 + s0 + tc] = tile[tc][tr + i*8];
}

// ---------------- flash attention, causal, GQA-fused, BN=128 ----------------
// block = 4 waves; both q-heads of one kv-head; BM=64 q rows, BN=128 keys/tile.
// This is the measured-best R3 structure (64KB LDS, P aliases sK) with ONE
// change: diagonal qi remap. Block->CU assignment gives each CU ids
// {c, c+256, c+512, c+768} which share x (256 = 8*32); with qi=31-x all four
// had IDENTICAL tmax -> worst CU did 4x32=128 serial tile-iters vs 66 avg.
// qi=(x+y)&31 spreads co-CU qi by 8 ({s,s+8,s+16,s+24} -> per-CU 52..80).
// K/V L2 sharing across same-y blocks is preserved: all blocks start at t=0
// and advance in lockstep regardless of qi (qi only sets the stop point).
__global__ __launch_bounds__(256, 2)
void attn_kernel(const bf16* __restrict__ Q, const bf16* __restrict__ Kg,
                 const bf16* __restrict__ Vt, bf16* __restrict__ Og) {
  __shared__ bf16 sK[32 * 512];    // 32KB: K chunks (nt 0..7)x(ks 0..3); P0|P1 after QK
  __shared__ bf16 sV[32 * 512];    // 32KB: chunks (ntd 0..7)x(ksk 0..3)
  int x = blockIdx.x, y = blockIdx.y;
  int qi = (x + y) & 31;           // diagonal remap (bijective per y)
  int bkv = y;                     // b*8 + kvh
  int b = bkv >> 3, kvh = bkv & 7;
  int tid = threadIdx.x, w = tid >> 6, l = tid & 63, lr = l & 15, lc = l >> 4;
  const bf16* Qb0 = Q + ((size_t)(b*16 + kvh*2) * 2048 + qi*64) * 128;
  const bf16* Qb1 = Qb0 + (size_t)2048 * 128;
  const bf16* Kb  = Kg + (size_t)bkv * 2048 * 128;
  const bf16* Vb  = Vt + (size_t)bkv * 128 * 2048;
  bf16x8 qf0[4], qf1[4];
  for (int ks = 0; ks < 4; ++ks) {
    size_t off = (size_t)(w*16 + lr) * 128 + ks*32 + lc*8;
    qf0[ks] = *(const bf16x8*)(Qb0 + off);
    qf1[ks] = *(const bf16x8*)(Qb1 + off);
  }
  f32x4 o0[8] = {}, o1[8] = {};
  float l0[4] = {0.f,0.f,0.f,0.f}, l1[4] = {0.f,0.f,0.f,0.f};
  int qrow = qi*64 + w*16 + lc*4;      // + r
  bf16* sP0 = sK + w * 2048;           // 16KB half: per-wave [16 q][128 key], XOR swz
  bf16* sP1 = sK + 8192 + w * 2048;    // head 1 half
  int tmax = (qi + 2) >> 1;            // ceil((qi*64+64)/128); last key read = 2047
  for (int t = 0; t < tmax; ++t) {
    __syncthreads();                   // P reads of t-1 retired; safe to restage sK
    for (int i = 0; i < 8; ++i) {
      int id = w*8 + i;
      int nt = id >> 2, ks = id & 3;
      gload16(Kb + (size_t)(t*128 + nt*16 + lr) * 128 + ks*32 + lc*8, sK + id*512);
      gload16(Vb + (size_t)(nt*16 + lr) * 2048 + t*128 + ks*32 + lc*8, sV + id*512);
    }
    __syncthreads();
    // S = Q K^T for both heads; K fragments loaded once
    f32x4 s0[8] = {}, s1[8] = {};
    for (int nt = 0; nt < 8; ++nt)
      for (int ks = 0; ks < 4; ++ks) {
        bf16x8 kf = *(const bf16x8*)(sK + (nt*4 + ks)*512 + l*8);
        s0[nt] = mfma16(qf0[ks], kf, s0[nt]);
        s1[nt] = mfma16(qf1[ks], kf, s1[nt]);
      }
    // causal mask: only the last tile needs it (block-uniform branch)
    if (t == tmax - 1) {
      for (int nt = 0; nt < 8; ++nt) {
        int col = t*128 + nt*16 + lr;
        for (int r = 0; r < 4; ++r)
          if (col > qrow + r) { s0[nt][r] = -1e30f; s1[nt][r] = -1e30f; }
      }
    }
    __syncthreads();                   // all QK reads of sK done -> P may overwrite
    // P swizzle: addr = (key>>6)*1024 + q*64 + (((key>>3)&7 ^ (q&7))*8) + (key&7)
    // both heads written to disjoint halves, single wait, then both read back
    for (int nt = 0; nt < 8; ++nt) {
      int hi6 = (nt >> 2) * 1024;
      int blk = (nt*2 + (lr >> 3)) & 7;
      int off = lr & 7;
      for (int r = 0; r < 4; ++r) {
        int q = lc*4 + r;
        int addr = hi6 + q*64 + ((blk ^ (q & 7)) * 8) + off;
        float p0 = __builtin_amdgcn_exp2f(s0[nt][r]);
        float p1 = __builtin_amdgcn_exp2f(s1[nt][r]);
        l0[r] += p0;
        l1[r] += p1;
        sP0[addr] = (bf16)p0;
        sP1[addr] = (bf16)p1;
      }
    }
    asm volatile("s_waitcnt lgkmcnt(0)" ::: "memory");
    __builtin_amdgcn_sched_barrier(0);
    bf16x8 pf0[4], pf1[4];
    for (int ks = 0; ks < 4; ++ks) {
      int ra = (ks >> 1)*1024 + lr*64 + ((((ks & 1)*4 + lc) ^ (lr & 7)) * 8);
      pf0[ks] = *(const bf16x8*)(sP0 + ra);
      pf1[ks] = *(const bf16x8*)(sP1 + ra);
    }
    // PV: V fragments read once, feed both heads
    for (int nt = 0; nt < 8; ++nt)
      for (int ks = 0; ks < 4; ++ks) {
        bf16x8 vf = *(const bf16x8*)(sV + (nt*4 + ks)*512 + l*8);
        o0[nt] = mfma16(pf0[ks], vf, o0[nt]);
        o1[nt] = mfma16(pf1[ks], vf, o1[nt]);
      }
  }
  // deferred l reduction: one shuffle ladder for the whole kernel
  for (int msk = 1; msk < 16; msk <<= 1)
    for (int r = 0; r < 4; ++r) {
      l0[r] += __shfl_xor(l0[r], msk, 64);
      l1[r] += __shfl_xor(l1[r], msk, 64);
    }
  for (int r = 0; r < 4; ++r) {
    float inv0 = 1.f / l0[r];
    float inv1 = 1.f / l1[r];
    size_t row = (size_t)(b*2048) + qi*64 + w*16 + lc*4 + r;
    size_t base0 = row * 2048 + (kvh*2) * 128;
    for (int nt = 0; nt < 8; ++nt) {
      Og[base0 + nt*16 + lr]       = (bf16)(o0[nt][r] * inv0);
      Og[base0 + 128 + nt*16 + lr] = (bf16)(o1[nt][r] * inv1);
    }
  }
}

extern "C" void kernel_launch(void* const* d_in, const int* in_sizes, int n_in,
                              void* d_out, int out_size, void* d_ws, size_t ws_size,
                              hipStream_t stream) {
  (void)in_sizes; (void)n_in; (void)out_size; (void)ws_size;
  const float* x  = (const float*)d_in[0];
  const float* cs = (const float*)d_in[1];
  const float* sn = (const float*)d_in[2];
  const float* Wq = (const float*)d_in[3];
  const float* Wk = (const float*)d_in[4];
  const float* Wv = (const float*)d_in[5];
  const float* Wo = (const float*)d_in[6];
  float* out = (float*)d_out;

  char* p = (char*)d_ws;
  bf16* xb    = (bf16*)p;  p += (size_t)8192*2048*2;    // x bf16
  bf16* Wt    = (bf16*)p;  p += (size_t)4096*2048*2;    // [Wq|Wk|Wv]^T bf16
  bf16* Wot   = (bf16*)p;  p += (size_t)2048*2048*2;    // Wo^T bf16
  bf16* Qr    = (bf16*)p;  p += (size_t)64*2048*128*2;  // Q roped [bh][s][d]
  bf16* Kr    = (bf16*)p;  p += (size_t)32*2048*128*2;  // K roped [bkv][s][d]
  bf16* Vbuf  = (bf16*)p;  p += (size_t)8192*1024*2;    // V [b*2048+s][kvh*128+d]
  bf16* Vtb   = (bf16*)p;  p += (size_t)32*2048*128*2;  // V^T [bkv][d][s]
  bf16* attnb = (bf16*)p;  p += (size_t)8192*2048*2;    // attention out

  cast_f32_bf16<<<4194304/256, 256, 0, stream>>>((const float4*)x, xb, 4194304);
  transpose_cast<<<dim3(64,64), 256, 0, stream>>>(Wq, Wt, 2048, 2048);
  transpose_cast<<<dim3(32,64), 256, 0, stream>>>(Wk, Wt + (size_t)2048*2048, 2048, 1024);
  transpose_cast<<<dim3(32,64), 256, 0, stream>>>(Wv, Wt + (size_t)3072*2048, 2048, 1024);
  transpose_cast<<<dim3(64,64), 256, 0, stream>>>(Wo, Wot, 2048, 2048);
  gemm256_rope<<<dim3(512), 512, 0, stream>>>(xb, Wt, cs, sn, Qr, Kr, Vbuf);
  v_transpose<<<dim3(64,4,32), 256, 0, stream>>>(Vbuf, Vtb);
  attn_kernel<<<dim3(32,32), 256, 0, stream>>>(Qr, Kr, Vtb, attnb);
  gemm256_out<<<dim3(256), 512, 0, stream>>>(attnb, Wot, out);
}